// Round 6
// baseline (857.299 us; speedup 1.0000x reference)
//
#include <hip/hip_runtime.h>
#include <hip/hip_bf16.h>

#define N_ 4096      // E*S
#define VOBS 128
#define KOBS 32
#define H_ 256
#define L_ 32
#define VCOMM 32

typedef __attribute__((ext_vector_type(8))) short short8;
typedef __attribute__((ext_vector_type(4))) float floatx4;

__device__ __forceinline__ float prelu_f(float x, float a){ return x >= 0.f ? x : a*x; }
__device__ __forceinline__ ushort f2bf(float x){
  unsigned int u = __float_as_uint(x);
  u = (u + 0x7FFFu + ((u >> 16) & 1u)) >> 16;
  return (ushort)u;
}
__device__ __forceinline__ float bf2f(ushort x){
  unsigned int u = ((unsigned int)x) << 16;
  return __uint_as_float(u);
}

// ---------------- obs path ----------------

__global__ __launch_bounds__(256) void k_idx(const float* __restrict__ obs, int* __restrict__ idx){
  const int n = blockIdx.x*4 + (threadIdx.x >> 6);
  const int lane = threadIdx.x & 63;
  float v0 = obs[(size_t)n*VOBS + lane];
  float v1 = obs[(size_t)n*VOBS + 64 + lane];
  unsigned long long m0 = __ballot(v0 > 0.5f);
  unsigned long long m1 = __ballot(v1 > 0.5f);
  unsigned long long lt = (1ull << lane) - 1ull;
  if (v0 > 0.5f){
    int pos = __popcll(m0 & lt);
    if (pos < KOBS) idx[n*KOBS + pos] = lane;
  }
  if (v1 > 0.5f){
    int pos = __popcll(m0) + __popcll(m1 & lt);
    if (pos < KOBS) idx[n*KOBS + pos] = 64 + lane;
  }
}

__global__ __launch_bounds__(256) void k_contrib(
    const float* __restrict__ obs_emb, const float* __restrict__ a_emb_p,
    const float* __restrict__ obs_W, float* __restrict__ contrib){
  const int k = blockIdx.x;
  const int vbase = blockIdx.y*16;
  const int tid = threadIdx.x;
  __shared__ float pe[16][H_];
  float a = a_emb_p[0];
  for (int i = tid; i < 16*H_; i += 256){
    int v = i >> 8, j = i & 255;
    pe[v][j] = prelu_f(obs_emb[(size_t)(vbase+v)*H_ + j], a);
  }
  __syncthreads();
  float acc[16];
  #pragma unroll
  for (int v = 0; v < 16; ++v) acc[v] = 0.f;
  for (int j = 0; j < H_; ++j){
    float w = obs_W[((size_t)(k*H_ + j))*H_ + tid];
    #pragma unroll
    for (int v = 0; v < 16; ++v) acc[v] += pe[v][j]*w;
  }
  for (int v = 0; v < 16; ++v)
    contrib[((size_t)((vbase+v)*KOBS + k))*H_ + tid] = acc[v];
}

__global__ __launch_bounds__(256) void k_obs_o(
    const int* __restrict__ idx, const float* __restrict__ contrib,
    const float* __restrict__ obs_b, const float* __restrict__ obs_a_p,
    float* __restrict__ out){
  const int n = blockIdx.x, tid = threadIdx.x;
  __shared__ int id[KOBS];
  if (tid < KOBS) id[tid] = idx[n*KOBS + tid];
  __syncthreads();
  float acc = obs_b[tid];
  #pragma unroll 8
  for (int k = 0; k < KOBS; ++k)
    acc += contrib[((size_t)(id[k]*KOBS + k))*H_ + tid];
  out[(size_t)n*512 + tid] = prelu_f(acc, obs_a_p[0]);
}

// ---------------- comm path ----------------

__global__ void k_tok(const float* __restrict__ comm, int* __restrict__ tok){
  int i = blockIdx.x*blockDim.x + threadIdx.x;
  if (i >= N_*L_) return;
  const float4* p = (const float4*)(comm + (size_t)i*VCOMM);
  float best = -1e30f; int bi = 0;
  #pragma unroll
  for (int j = 0; j < 8; ++j){
    float4 q = p[j];
    if (q.x > best){ best = q.x; bi = j*4+0; }
    if (q.y > best){ best = q.y; bi = j*4+1; }
    if (q.z > best){ best = q.z; bi = j*4+2; }
    if (q.w > best){ best = q.w; bi = j*4+3; }
  }
  tok[i] = bi;
}

__global__ void k_P(const float* __restrict__ comm_emb, const float* __restrict__ ca_p,
                    const float* __restrict__ cw1, const float* __restrict__ cw3,
                    const float* __restrict__ cw5, const float* __restrict__ cw7,
                    float* __restrict__ P){
  const int slot = blockIdx.x, v = blockIdx.y, c = threadIdx.x;
  int g, tap;
  if (slot == 0){ g=0; tap=0; }
  else if (slot < 4){ g=1; tap=slot-1; }
  else if (slot < 9){ g=2; tap=slot-4; }
  else { g=3; tap=slot-9; }
  const float* w; int ks;
  if (g==0){ w=cw1; ks=1; } else if (g==1){ w=cw3; ks=3; }
  else if (g==2){ w=cw5; ks=5; } else { w=cw7; ks=7; }
  float a = ca_p[0];
  float acc = 0.f;
  for (int h = 0; h < H_; ++h){
    float e = prelu_f(comm_emb[(size_t)v*H_ + h], a);
    acc += e * w[(size_t)(c*H_ + h)*ks + tap];
  }
  P[(size_t)(slot*VCOMM + v)*64 + c] = acc;
}

template<int KS, bool APPLY>
__device__ __forceinline__ void conv_work(
    const float* __restrict__ Ps, const int tk[16][L_], int wave, int lane,
    float bias, float scale, float shift, float ca,
    ushort* __restrict__ ynorm, int nbase, int g,
    float* s_out, float* q_out)
{
  constexpr int PAD = (KS-1)/2;
  float s = 0.f, sq = 0.f;
  for (int j = 0; j < 4; ++j){
    const int nn = wave*4 + j;
    int base[L_];
    #pragma unroll
    for (int l = 0; l < L_; ++l) base[l] = tk[nn][l]*64 + lane;
    #pragma unroll
    for (int l = 0; l < L_; ++l){
      float acc = bias;
      #pragma unroll
      for (int t = 0; t < KS; ++t){
        const int lp = l + t - PAD;
        if (lp >= 0 && lp < L_) acc += Ps[t*2048 + base[lp]];
      }
      if (APPLY){
        float y = prelu_f(fmaf(acc, scale, shift), ca);
        ynorm[((size_t)l*N_ + (nbase+nn))*H_ + g*64 + lane] = f2bf(y);
      } else {
        s += acc; sq += acc*acc;
      }
    }
  }
  *s_out = s; *q_out = sq;
}

__global__ __launch_bounds__(256) void k_conv_stats(
    const int* __restrict__ tok, const float* __restrict__ P,
    const float* __restrict__ cb1, const float* __restrict__ cb3,
    const float* __restrict__ cb5, const float* __restrict__ cb7,
    float* __restrict__ stats){
  const int g = blockIdx.y;
  const int nbase = blockIdx.x*16;
  const int tid = threadIdx.x, lane = tid & 63, wave = tid >> 6;
  const int ks = 2*g + 1, base = g*g;
  const float* cb = (g==0)?cb1:(g==1)?cb3:(g==2)?cb5:cb7;
  const float bias = cb[lane];
  __shared__ float Ps[7*2048];
  __shared__ int tk[16][L_];
  __shared__ float red_s[4][64], red_q[4][64];
  for (int i = tid; i < ks*512; i += 256)
    ((float4*)Ps)[i] = ((const float4*)(P + base*2048))[i];
  for (int i = tid; i < 16*L_; i += 256)
    tk[i>>5][i&31] = tok[(size_t)(nbase + (i>>5))*L_ + (i&31)];
  __syncthreads();
  float s = 0.f, sq = 0.f;
  switch (g){
    case 0: conv_work<1,false>(Ps, tk, wave, lane, bias, 0,0,0, nullptr, nbase, g, &s, &sq); break;
    case 1: conv_work<3,false>(Ps, tk, wave, lane, bias, 0,0,0, nullptr, nbase, g, &s, &sq); break;
    case 2: conv_work<5,false>(Ps, tk, wave, lane, bias, 0,0,0, nullptr, nbase, g, &s, &sq); break;
    default: conv_work<7,false>(Ps, tk, wave, lane, bias, 0,0,0, nullptr, nbase, g, &s, &sq); break;
  }
  red_s[wave][lane] = s; red_q[wave][lane] = sq;
  __syncthreads();
  if (wave == 0){
    float ts = red_s[0][lane]+red_s[1][lane]+red_s[2][lane]+red_s[3][lane];
    float tq = red_q[0][lane]+red_q[1][lane]+red_q[2][lane]+red_q[3][lane];
    atomicAdd(&stats[g*64 + lane], ts);
    atomicAdd(&stats[256 + g*64 + lane], tq);
  }
}

__global__ void k_bn_fin(const float* __restrict__ stats, const float* __restrict__ bn_g,
                         const float* __restrict__ bn_b, float* __restrict__ ss){
  int t = threadIdx.x;
  const float cnt = (float)(N_*L_);
  float m = stats[t]/cnt;
  float v = stats[256+t]/cnt - m*m;
  float sc = bn_g[t] / sqrtf(v + 1e-5f);
  ss[t] = sc; ss[256+t] = bn_b[t] - m*sc;
}

__global__ __launch_bounds__(256) void k_conv_apply(
    const int* __restrict__ tok, const float* __restrict__ P,
    const float* __restrict__ cb1, const float* __restrict__ cb3,
    const float* __restrict__ cb5, const float* __restrict__ cb7,
    const float* __restrict__ ss, const float* __restrict__ cnn_a_p,
    ushort* __restrict__ ynorm){
  const int g = blockIdx.y;
  const int nbase = blockIdx.x*16;
  const int tid = threadIdx.x, lane = tid & 63, wave = tid >> 6;
  const int ks = 2*g + 1, base = g*g;
  const float* cb = (g==0)?cb1:(g==1)?cb3:(g==2)?cb5:cb7;
  const float bias = cb[lane];
  const float scale = ss[g*64 + lane], shift = ss[256 + g*64 + lane];
  const float ca = cnn_a_p[0];
  __shared__ float Ps[7*2048];
  __shared__ int tk[16][L_];
  for (int i = tid; i < ks*512; i += 256)
    ((float4*)Ps)[i] = ((const float4*)(P + base*2048))[i];
  for (int i = tid; i < 16*L_; i += 256)
    tk[i>>5][i&31] = tok[(size_t)(nbase + (i>>5))*L_ + (i&31)];
  __syncthreads();
  float s, q;
  switch (g){
    case 0: conv_work<1,true>(Ps, tk, wave, lane, bias, scale, shift, ca, ynorm, nbase, g, &s, &q); break;
    case 1: conv_work<3,true>(Ps, tk, wave, lane, bias, scale, shift, ca, ynorm, nbase, g, &s, &q); break;
    case 2: conv_work<5,true>(Ps, tk, wave, lane, bias, scale, shift, ca, ynorm, nbase, g, &s, &q); break;
    default: conv_work<7,true>(Ps, tk, wave, lane, bias, scale, shift, ca, ynorm, nbase, g, &s, &q); break;
  }
}

// ---------------- GRU scan ----------------

// Both weight tables: [c = g*256 + u][k] bf16 row-major (gemm-col-major transpose).
__global__ void k_WT3(const float* __restrict__ Wx, const float* __restrict__ Wh,
                      ushort* __restrict__ WxT3, ushort* __restrict__ WhT3p){
  int id = blockIdx.x*256 + threadIdx.x;  // 0..196607; id = g*65536 + u*256 + k
  int g = id >> 16, u = (id >> 8) & 255, k = id & 255;
  WxT3[id]  = f2bf(Wx[(size_t)g*65536 + k*256 + u]);
  WhT3p[id] = f2bf(Wh[(size_t)g*65536 + k*256 + u]);
}

// xp[row][c] = Y[row][:] @ WxT3[c][:], row = l_local*4096 + n, c = g*256+u.
// A-frags direct from global (L2-warm), B staged in LDS, transposed coalesced
// stores. grid 512, 256 thr, dyn LDS 76800 B -> 2 blocks/CU, 8 waves/CU.
__global__ __launch_bounds__(256) void k_xproj(
    const ushort* __restrict__ Y, const ushort* __restrict__ WxT3,
    ushort* __restrict__ xp)
{
  extern __shared__ __align__(16) char smem[];
  ushort* Bs = (ushort*)smem;             // [128][264] = 67584 B
  ushort* Tb = (ushort*)smem + 33792;     // [4][16][72] = 9216 B
  const int bm = blockIdx.x;
  const int tid = threadIdx.x, lane = tid & 63, w = tid >> 6;
  const int wm = w >> 1, wn = w & 1;
  const int quad = lane >> 4, l16 = lane & 15;
  for (int bn = 0; bn < 6; ++bn){
    __syncthreads();
    #pragma unroll
    for (int i = 0; i < 16; ++i){
      int id = i*256 + tid;
      int row = id >> 5, cc = id & 31;
      *(uint4*)&Bs[row*264 + cc*8] = *(const uint4*)(WxT3 + ((size_t)(bn*128 + row))*H_ + cc*8);
    }
    __syncthreads();
    floatx4 acc[4][4];
    #pragma unroll
    for (int i = 0; i < 4; ++i)
      #pragma unroll
      for (int j = 0; j < 4; ++j)
        acc[i][j] = (floatx4){0.f,0.f,0.f,0.f};
    #pragma unroll
    for (int kt = 0; kt < 8; ++kt){
      short8 a[4], b[4];
      #pragma unroll
      for (int mi = 0; mi < 4; ++mi)
        a[mi] = *(const short8*)(Y + ((size_t)(bm*128 + wm*64 + mi*16 + l16))*H_ + kt*32 + quad*8);
      #pragma unroll
      for (int ni = 0; ni < 4; ++ni)
        b[ni] = *(const short8*)&Bs[(wn*64 + ni*16 + l16)*264 + kt*32 + quad*8];
      #pragma unroll
      for (int mi = 0; mi < 4; ++mi)
        #pragma unroll
        for (int ni = 0; ni < 4; ++ni)
          acc[mi][ni] = __builtin_amdgcn_mfma_f32_16x16x32_bf16(a[mi], b[ni], acc[mi][ni], 0,0,0);
    }
    ushort* Tw = Tb + w*16*72;
    #pragma unroll
    for (int mi = 0; mi < 4; ++mi){
      #pragma unroll
      for (int ni = 0; ni < 4; ++ni)
        #pragma unroll
        for (int r = 0; r < 4; ++r)
          Tw[(quad*4 + r)*72 + ni*16 + l16] = f2bf(acc[mi][ni][r]);
      // wave-internal LDS round-trip (in-order within wave)
      #pragma unroll
      for (int i = 0; i < 2; ++i){
        int rr = i*8 + (lane >> 3);
        int cc = lane & 7;
        int grow = bm*128 + wm*64 + mi*16 + rr;
        *(uint4*)(xp + (size_t)grow*768 + bn*128 + wn*64 + cc*8) = *(const uint4*)&Tw[rr*72 + cc*8];
      }
    }
  }
}

// Persistent 16-step scan, zero inter-block deps. grid 128 x 1024 threads;
// block owns 32 rows fully. A (h) in LDS bf16; B (Wh) read DIRECTLY from
// global per MFMA (L2-resident 393 KB) -> no staging barriers. h fp32 in regs.
// dyn LDS = 32*264*2 + 32*772*4 = 115712 B.
__global__ __launch_bounds__(1024) void k_scan(
    const ushort* __restrict__ Whp, const ushort* __restrict__ xp,
    const float* __restrict__ bx, const float* __restrict__ bh,
    const float* __restrict__ h_in, const ushort* __restrict__ hbf_in,
    float* __restrict__ h_out, ushort* __restrict__ hbf_out, int first)
{
  extern __shared__ __align__(16) char smem[];
  ushort* hA = (ushort*)smem;                 // [32][264]
  float*  Ep = (float*)(smem + 16896);        // [32][772]
  const int tid = threadIdx.x;
  const int lane = tid & 63, w = tid >> 6;    // 16 waves; wave cols w*48..+48
  const int quad = lane >> 4, l16 = lane & 15;
  const int n0 = blockIdx.x*32;
  const int u = tid & 255, rq = tid >> 8;     // gate map: 8 rows per thread

  float hreg[8];
  if (first){
    #pragma unroll
    for (int r = 0; r < 8; ++r) hreg[r] = 0.f;
    for (int i = tid; i < 32*264; i += 1024) hA[i] = 0;
  } else {
    #pragma unroll
    for (int r = 0; r < 8; ++r){
      int row = rq*8 + r;
      hreg[r] = h_in[(size_t)(n0+row)*H_ + u];
      hA[row*264 + u] = hbf_in[(size_t)(n0+row)*H_ + u];
    }
  }
  const float b0 = bx[u] + bh[u];
  const float b1 = bx[256+u] + bh[256+u];
  const float b2x = bx[512+u], b2h = bh[512+u];
  __syncthreads();

  for (int l = 0; l < 16; ++l){
    const ushort* xpl = xp + (size_t)l*N_*768;
    // xp prefetch (HBM latency overlapped with MFMA phase)
    float xr[8], xz[8], xn[8];
    #pragma unroll
    for (int r = 0; r < 8; ++r){
      const ushort* q = xpl + (size_t)(n0 + rq*8 + r)*768;
      xr[r] = bf2f(q[u]); xz[r] = bf2f(q[256+u]); xn[r] = bf2f(q[512+u]);
    }
    floatx4 acc[2][3];
    #pragma unroll
    for (int mi = 0; mi < 2; ++mi)
      #pragma unroll
      for (int ni = 0; ni < 3; ++ni)
        acc[mi][ni] = (floatx4){0.f,0.f,0.f,0.f};
    #pragma unroll
    for (int kt = 0; kt < 8; ++kt){
      short8 a0 = *(const short8*)&hA[(     l16)*264 + kt*32 + quad*8];
      short8 a1 = *(const short8*)&hA[(16 + l16)*264 + kt*32 + quad*8];
      #pragma unroll
      for (int ni = 0; ni < 3; ++ni){
        const int c = w*48 + ni*16 + l16;
        short8 b = *(const short8*)(Whp + (size_t)c*H_ + kt*32 + quad*8);
        acc[0][ni] = __builtin_amdgcn_mfma_f32_16x16x32_bf16(a0, b, acc[0][ni], 0,0,0);
        acc[1][ni] = __builtin_amdgcn_mfma_f32_16x16x32_bf16(a1, b, acc[1][ni], 0,0,0);
      }
    }
    __syncthreads();   // hA reads + prev Ep reads complete
    #pragma unroll
    for (int mi = 0; mi < 2; ++mi)
      #pragma unroll
      for (int ni = 0; ni < 3; ++ni)
        #pragma unroll
        for (int r = 0; r < 4; ++r)
          Ep[(mi*16 + quad*4 + r)*772 + w*48 + ni*16 + l16] = acc[mi][ni][r];
    __syncthreads();   // Ep visible
    #pragma unroll
    for (int r = 0; r < 8; ++r){
      int row = rq*8 + r;
      float hr = Ep[row*772 +       u];
      float hz = Ep[row*772 + 256 + u];
      float hn = Ep[row*772 + 512 + u];
      float rg = 1.f/(1.f + __expf(-(xr[r] + hr + b0)));
      float zg = 1.f/(1.f + __expf(-(xz[r] + hz + b1)));
      float na = xn[r] + b2x + rg*(hn + b2h);
      float ng = 1.f - 2.f/(1.f + __expf(2.f*na));
      hreg[r] = ng*(1.f - zg) + hreg[r]*zg;
      hA[row*264 + u] = f2bf(hreg[r]);
    }
    __syncthreads();   // hA visible before next MFMA
  }
  #pragma unroll
  for (int r = 0; r < 8; ++r){
    int row = rq*8 + r;
    h_out[(size_t)(n0+row)*H_ + u] = hreg[r];
    hbf_out[(size_t)(n0+row)*H_ + u] = f2bf(hreg[r]);
  }
}

// c = prelu(prelu(h,a1) @ lin_W + lin_b, a2) -> out[..., 256:512]
__global__ __launch_bounds__(256) void k_final(
    const float* __restrict__ h, const float* __restrict__ a1p,
    const float* __restrict__ lin_W, const float* __restrict__ lin_b,
    const float* __restrict__ a2p, float* __restrict__ out){
  const int nbase = blockIdx.x*16, tid = threadIdx.x;
  __shared__ float hp[16][H_];
  const float a1 = a1p[0], a2 = a2p[0];
  for (int i = tid; i < 16*H_; i += 256)
    hp[i>>8][i&255] = prelu_f(h[(size_t)(nbase + (i>>8))*H_ + (i&255)], a1);
  __syncthreads();
  float acc[16];
  const float b = lin_b[tid];
  #pragma unroll
  for (int r = 0; r < 16; ++r) acc[r] = b;
  for (int j = 0; j < H_; ++j){
    float w = lin_W[(size_t)j*H_ + tid];
    #pragma unroll
    for (int r = 0; r < 16; ++r) acc[r] += hp[r][j]*w;
  }
  for (int r = 0; r < 16; ++r)
    out[(size_t)(nbase+r)*512 + 256 + tid] = prelu_f(acc[r], a2);
}

extern "C" void kernel_launch(void* const* d_in, const int* in_sizes, int n_in,
                              void* d_out, int out_size, void* d_ws, size_t ws_size,
                              hipStream_t stream) {
  (void)in_sizes; (void)n_in; (void)out_size; (void)ws_size;
  const float* obs      = (const float*)d_in[0];
  const float* comm     = (const float*)d_in[1];
  const float* obs_emb  = (const float*)d_in[2];
  const float* obs_a_emb= (const float*)d_in[3];
  const float* obs_W    = (const float*)d_in[4];
  const float* obs_b    = (const float*)d_in[5];
  const float* obs_a    = (const float*)d_in[6];
  const float* comm_emb = (const float*)d_in[7];
  const float* comm_a   = (const float*)d_in[8];
  const float* cw1      = (const float*)d_in[9];
  const float* cb1      = (const float*)d_in[10];
  const float* cw3      = (const float*)d_in[11];
  const float* cb3      = (const float*)d_in[12];
  const float* cw5      = (const float*)d_in[13];
  const float* cb5      = (const float*)d_in[14];
  const float* cw7      = (const float*)d_in[15];
  const float* cb7      = (const float*)d_in[16];
  const float* bn_g     = (const float*)d_in[17];
  const float* bn_b     = (const float*)d_in[18];
  const float* cnn_a    = (const float*)d_in[19];
  const float* Wx       = (const float*)d_in[20];
  const float* bx       = (const float*)d_in[21];
  const float* Wh       = (const float*)d_in[22];
  const float* bh       = (const float*)d_in[23];
  const float* lin_a1   = (const float*)d_in[24];
  const float* lin_W    = (const float*)d_in[25];
  const float* lin_b    = (const float*)d_in[26];
  const float* lin_a2   = (const float*)d_in[27];
  float* out = (float*)d_out;

  char* ws = (char*)d_ws;
  float*  contrib = (float*)(ws + 0);            // 4,194,304
  float*  P       = (float*)(ws + 4194304);      // 131,072
  int*    idx     = (int*)  (ws + 4325376);      // 524,288
  int*    tok     = (int*)  (ws + 4849664);      // 524,288
  float*  stats   = (float*)(ws + 5373952);      // 2,048
  float*  ss      = (float*)(ws + 5376000);      // 2,048
  ushort* WxT3    = (ushort*)(ws + 5378048);     // 393,216
  ushort* WhT3p   = (ushort*)(ws + 5771264);     // 393,216
  float*  h_a     = (float*)(ws + 6164480);      // 4,194,304
  float*  h_b     = (float*)(ws + 10358784);     // 4,194,304
  ushort* hbf_a   = (ushort*)(ws + 14553088);    // 2,097,152
  ushort* hbf_b   = (ushort*)(ws + 16650240);    // 2,097,152
  ushort* ynorm   = (ushort*)(ws + 18747392);    // 67,108,864
  ushort* xp      = (ushort*)(ws + 85856256);    // 100,663,296

  hipMemsetAsync(stats, 0, 512*sizeof(float), stream);

  k_idx<<<1024, 256, 0, stream>>>(obs, idx);
  k_tok<<<512, 256, 0, stream>>>(comm, tok);
  k_WT3<<<768, 256, 0, stream>>>(Wx, Wh, WxT3, WhT3p);
  k_P<<<dim3(16,32), 64, 0, stream>>>(comm_emb, comm_a, cw1, cw3, cw5, cw7, P);
  k_contrib<<<dim3(32,8), 256, 0, stream>>>(obs_emb, obs_a_emb, obs_W, contrib);
  k_obs_o<<<4096, 256, 0, stream>>>(idx, contrib, obs_b, obs_a, out);
  k_conv_stats<<<dim3(256,4), 256, 0, stream>>>(tok, P, cb1, cb3, cb5, cb7, stats);
  k_bn_fin<<<1, 256, 0, stream>>>(stats, bn_g, bn_b, ss);
  k_conv_apply<<<dim3(256,4), 256, 0, stream>>>(tok, P, cb1, cb3, cb5, cb7, ss, cnn_a, ynorm);

  // half 0: l = 0..15
  k_xproj<<<512, 256, 76800, stream>>>(ynorm, WxT3, xp);
  k_scan<<<128, 1024, 115712, stream>>>(WhT3p, xp, bx, bh, h_a, hbf_a, h_a, hbf_a, 1);
  // half 1: l = 16..31
  k_xproj<<<512, 256, 76800, stream>>>(ynorm + (size_t)16*N_*H_, WxT3, xp);
  k_scan<<<128, 1024, 115712, stream>>>(WhT3p, xp, bx, bh, h_a, hbf_a, h_b, hbf_b, 0);

  k_final<<<256, 256, 0, stream>>>(h_b, lin_a1, lin_W, lin_b, lin_a2, out);
}

// Round 7
// 553.383 us; speedup vs baseline: 1.5492x; 1.5492x over previous
//
#include <hip/hip_runtime.h>
#include <hip/hip_bf16.h>

#define N_ 4096      // E*S
#define VOBS 128
#define KOBS 32
#define H_ 256
#define L_ 32
#define VCOMM 32

typedef __attribute__((ext_vector_type(8))) short short8;
typedef __attribute__((ext_vector_type(4))) float floatx4;

__device__ __forceinline__ float prelu_f(float x, float a){ return x >= 0.f ? x : a*x; }
__device__ __forceinline__ ushort f2bf(float x){
  unsigned int u = __float_as_uint(x);
  u = (u + 0x7FFFu + ((u >> 16) & 1u)) >> 16;
  return (ushort)u;
}
__device__ __forceinline__ float bf2f(ushort x){
  unsigned int u = ((unsigned int)x) << 16;
  return __uint_as_float(u);
}

// async global->LDS 16B per lane; lds dest wave-uniform base (+lane*16 in HW)
__device__ __forceinline__ void gl_lds16(const ushort* __restrict__ src, ushort* dst){
  __builtin_amdgcn_global_load_lds(
      (const __attribute__((address_space(1))) unsigned int*)src,
      (__attribute__((address_space(3))) unsigned int*)dst, 16, 0, 0);
}

// ---------------- obs path ----------------

__global__ __launch_bounds__(256) void k_idx(const float* __restrict__ obs, int* __restrict__ idx){
  const int n = blockIdx.x*4 + (threadIdx.x >> 6);
  const int lane = threadIdx.x & 63;
  float v0 = obs[(size_t)n*VOBS + lane];
  float v1 = obs[(size_t)n*VOBS + 64 + lane];
  unsigned long long m0 = __ballot(v0 > 0.5f);
  unsigned long long m1 = __ballot(v1 > 0.5f);
  unsigned long long lt = (1ull << lane) - 1ull;
  if (v0 > 0.5f){
    int pos = __popcll(m0 & lt);
    if (pos < KOBS) idx[n*KOBS + pos] = lane;
  }
  if (v1 > 0.5f){
    int pos = __popcll(m0) + __popcll(m1 & lt);
    if (pos < KOBS) idx[n*KOBS + pos] = 64 + lane;
  }
}

__global__ __launch_bounds__(256) void k_contrib(
    const float* __restrict__ obs_emb, const float* __restrict__ a_emb_p,
    const float* __restrict__ obs_W, float* __restrict__ contrib){
  const int k = blockIdx.x;
  const int vbase = blockIdx.y*16;
  const int tid = threadIdx.x;
  __shared__ float pe[16][H_];
  float a = a_emb_p[0];
  for (int i = tid; i < 16*H_; i += 256){
    int v = i >> 8, j = i & 255;
    pe[v][j] = prelu_f(obs_emb[(size_t)(vbase+v)*H_ + j], a);
  }
  __syncthreads();
  float acc[16];
  #pragma unroll
  for (int v = 0; v < 16; ++v) acc[v] = 0.f;
  for (int j = 0; j < H_; ++j){
    float w = obs_W[((size_t)(k*H_ + j))*H_ + tid];
    #pragma unroll
    for (int v = 0; v < 16; ++v) acc[v] += pe[v][j]*w;
  }
  for (int v = 0; v < 16; ++v)
    contrib[((size_t)((vbase+v)*KOBS + k))*H_ + tid] = acc[v];
}

__global__ __launch_bounds__(256) void k_obs_o(
    const int* __restrict__ idx, const float* __restrict__ contrib,
    const float* __restrict__ obs_b, const float* __restrict__ obs_a_p,
    float* __restrict__ out){
  const int n = blockIdx.x, tid = threadIdx.x;
  __shared__ int id[KOBS];
  if (tid < KOBS) id[tid] = idx[n*KOBS + tid];
  __syncthreads();
  float acc = obs_b[tid];
  #pragma unroll 8
  for (int k = 0; k < KOBS; ++k)
    acc += contrib[((size_t)(id[k]*KOBS + k))*H_ + tid];
  out[(size_t)n*512 + tid] = prelu_f(acc, obs_a_p[0]);
}

// ---------------- comm path ----------------

__global__ void k_tok(const float* __restrict__ comm, int* __restrict__ tok){
  int i = blockIdx.x*blockDim.x + threadIdx.x;
  if (i >= N_*L_) return;
  const float4* p = (const float4*)(comm + (size_t)i*VCOMM);
  float best = -1e30f; int bi = 0;
  #pragma unroll
  for (int j = 0; j < 8; ++j){
    float4 q = p[j];
    if (q.x > best){ best = q.x; bi = j*4+0; }
    if (q.y > best){ best = q.y; bi = j*4+1; }
    if (q.z > best){ best = q.z; bi = j*4+2; }
    if (q.w > best){ best = q.w; bi = j*4+3; }
  }
  tok[i] = bi;
}

__global__ void k_P(const float* __restrict__ comm_emb, const float* __restrict__ ca_p,
                    const float* __restrict__ cw1, const float* __restrict__ cw3,
                    const float* __restrict__ cw5, const float* __restrict__ cw7,
                    float* __restrict__ P){
  const int slot = blockIdx.x, v = blockIdx.y, c = threadIdx.x;
  int g, tap;
  if (slot == 0){ g=0; tap=0; }
  else if (slot < 4){ g=1; tap=slot-1; }
  else if (slot < 9){ g=2; tap=slot-4; }
  else { g=3; tap=slot-9; }
  const float* w; int ks;
  if (g==0){ w=cw1; ks=1; } else if (g==1){ w=cw3; ks=3; }
  else if (g==2){ w=cw5; ks=5; } else { w=cw7; ks=7; }
  float a = ca_p[0];
  float acc = 0.f;
  for (int h = 0; h < H_; ++h){
    float e = prelu_f(comm_emb[(size_t)v*H_ + h], a);
    acc += e * w[(size_t)(c*H_ + h)*ks + tap];
  }
  P[(size_t)(slot*VCOMM + v)*64 + c] = acc;
}

template<int KS, bool APPLY>
__device__ __forceinline__ void conv_work(
    const float* __restrict__ Ps, const int tk[16][L_], int wave, int lane,
    float bias, float scale, float shift, float ca,
    ushort* __restrict__ ynorm, int nbase, int g,
    float* s_out, float* q_out)
{
  constexpr int PAD = (KS-1)/2;
  float s = 0.f, sq = 0.f;
  for (int j = 0; j < 4; ++j){
    const int nn = wave*4 + j;
    int base[L_];
    #pragma unroll
    for (int l = 0; l < L_; ++l) base[l] = tk[nn][l]*64 + lane;
    #pragma unroll
    for (int l = 0; l < L_; ++l){
      float acc = bias;
      #pragma unroll
      for (int t = 0; t < KS; ++t){
        const int lp = l + t - PAD;
        if (lp >= 0 && lp < L_) acc += Ps[t*2048 + base[lp]];
      }
      if (APPLY){
        float y = prelu_f(fmaf(acc, scale, shift), ca);
        ynorm[((size_t)l*N_ + (nbase+nn))*H_ + g*64 + lane] = f2bf(y);
      } else {
        s += acc; sq += acc*acc;
      }
    }
  }
  *s_out = s; *q_out = sq;
}

__global__ __launch_bounds__(256) void k_conv_stats(
    const int* __restrict__ tok, const float* __restrict__ P,
    const float* __restrict__ cb1, const float* __restrict__ cb3,
    const float* __restrict__ cb5, const float* __restrict__ cb7,
    float* __restrict__ stats){
  const int g = blockIdx.y;
  const int nbase = blockIdx.x*16;
  const int tid = threadIdx.x, lane = tid & 63, wave = tid >> 6;
  const int ks = 2*g + 1, base = g*g;
  const float* cb = (g==0)?cb1:(g==1)?cb3:(g==2)?cb5:cb7;
  const float bias = cb[lane];
  __shared__ float Ps[7*2048];
  __shared__ int tk[16][L_];
  __shared__ float red_s[4][64], red_q[4][64];
  for (int i = tid; i < ks*512; i += 256)
    ((float4*)Ps)[i] = ((const float4*)(P + base*2048))[i];
  for (int i = tid; i < 16*L_; i += 256)
    tk[i>>5][i&31] = tok[(size_t)(nbase + (i>>5))*L_ + (i&31)];
  __syncthreads();
  float s = 0.f, sq = 0.f;
  switch (g){
    case 0: conv_work<1,false>(Ps, tk, wave, lane, bias, 0,0,0, nullptr, nbase, g, &s, &sq); break;
    case 1: conv_work<3,false>(Ps, tk, wave, lane, bias, 0,0,0, nullptr, nbase, g, &s, &sq); break;
    case 2: conv_work<5,false>(Ps, tk, wave, lane, bias, 0,0,0, nullptr, nbase, g, &s, &sq); break;
    default: conv_work<7,false>(Ps, tk, wave, lane, bias, 0,0,0, nullptr, nbase, g, &s, &sq); break;
  }
  red_s[wave][lane] = s; red_q[wave][lane] = sq;
  __syncthreads();
  if (wave == 0){
    float ts = red_s[0][lane]+red_s[1][lane]+red_s[2][lane]+red_s[3][lane];
    float tq = red_q[0][lane]+red_q[1][lane]+red_q[2][lane]+red_q[3][lane];
    atomicAdd(&stats[g*64 + lane], ts);
    atomicAdd(&stats[256 + g*64 + lane], tq);
  }
}

__global__ void k_bn_fin(const float* __restrict__ stats, const float* __restrict__ bn_g,
                         const float* __restrict__ bn_b, float* __restrict__ ss){
  int t = threadIdx.x;
  const float cnt = (float)(N_*L_);
  float m = stats[t]/cnt;
  float v = stats[256+t]/cnt - m*m;
  float sc = bn_g[t] / sqrtf(v + 1e-5f);
  ss[t] = sc; ss[256+t] = bn_b[t] - m*sc;
}

__global__ __launch_bounds__(256) void k_conv_apply(
    const int* __restrict__ tok, const float* __restrict__ P,
    const float* __restrict__ cb1, const float* __restrict__ cb3,
    const float* __restrict__ cb5, const float* __restrict__ cb7,
    const float* __restrict__ ss, const float* __restrict__ cnn_a_p,
    ushort* __restrict__ ynorm){
  const int g = blockIdx.y;
  const int nbase = blockIdx.x*16;
  const int tid = threadIdx.x, lane = tid & 63, wave = tid >> 6;
  const int ks = 2*g + 1, base = g*g;
  const float* cb = (g==0)?cb1:(g==1)?cb3:(g==2)?cb5:cb7;
  const float bias = cb[lane];
  const float scale = ss[g*64 + lane], shift = ss[256 + g*64 + lane];
  const float ca = cnn_a_p[0];
  __shared__ float Ps[7*2048];
  __shared__ int tk[16][L_];
  for (int i = tid; i < ks*512; i += 256)
    ((float4*)Ps)[i] = ((const float4*)(P + base*2048))[i];
  for (int i = tid; i < 16*L_; i += 256)
    tk[i>>5][i&31] = tok[(size_t)(nbase + (i>>5))*L_ + (i&31)];
  __syncthreads();
  float s, q;
  switch (g){
    case 0: conv_work<1,true>(Ps, tk, wave, lane, bias, scale, shift, ca, ynorm, nbase, g, &s, &q); break;
    case 1: conv_work<3,true>(Ps, tk, wave, lane, bias, scale, shift, ca, ynorm, nbase, g, &s, &q); break;
    case 2: conv_work<5,true>(Ps, tk, wave, lane, bias, scale, shift, ca, ynorm, nbase, g, &s, &q); break;
    default: conv_work<7,true>(Ps, tk, wave, lane, bias, scale, shift, ca, ynorm, nbase, g, &s, &q); break;
  }
}

// ---------------- GRU scan ----------------

// Both weight tables: [c = g*256 + u][k] bf16 row-major.
__global__ void k_WT3(const float* __restrict__ Wx, const float* __restrict__ Wh,
                      ushort* __restrict__ WxT3, ushort* __restrict__ WhT3p){
  int id = blockIdx.x*256 + threadIdx.x;  // id = g*65536 + u*256 + k
  int g = id >> 16, u = (id >> 8) & 255, k = id & 255;
  WxT3[id]  = f2bf(Wx[(size_t)g*65536 + k*256 + u]);
  WhT3p[id] = f2bf(Wh[(size_t)g*65536 + k*256 + u]);
}

// xp[row][c] = Y[row][:] @ WxT3[c][:].  grid 512, 256 thr, LB(256,2).
// A-frags (32 = 128 VGPR) loaded ONCE and held; B full-tile LDS per bn.
// dyn LDS = 67584 + 9216 = 76800 B -> 2 blocks/CU.
__global__ __launch_bounds__(256,2) void k_xproj(
    const ushort* __restrict__ Y, const ushort* __restrict__ WxT3,
    ushort* __restrict__ xp)
{
  extern __shared__ __align__(16) char smem[];
  ushort* Bs = (ushort*)smem;             // [128][264]
  ushort* Tb = (ushort*)smem + 33792;     // [4][16][72]
  const int bm = blockIdx.x;
  const int tid = threadIdx.x, lane = tid & 63, w = tid >> 6;
  const int wm = w >> 1, wn = w & 1;
  const int quad = lane >> 4, l16 = lane & 15;

  short8 Af[4][8];
  #pragma unroll
  for (int mi = 0; mi < 4; ++mi)
    #pragma unroll
    for (int kt = 0; kt < 8; ++kt)
      Af[mi][kt] = *(const short8*)(Y + ((size_t)(bm*128 + wm*64 + mi*16 + l16))*H_ + kt*32 + quad*8);

  for (int bn = 0; bn < 6; ++bn){
    __syncthreads();
    #pragma unroll
    for (int i = 0; i < 16; ++i){
      int id = i*256 + tid;
      int row = id >> 5, cc = id & 31;
      *(uint4*)&Bs[row*264 + cc*8] = *(const uint4*)(WxT3 + ((size_t)(bn*128 + row))*H_ + cc*8);
    }
    __syncthreads();
    floatx4 acc[4][4];
    #pragma unroll
    for (int i = 0; i < 4; ++i)
      #pragma unroll
      for (int j = 0; j < 4; ++j)
        acc[i][j] = (floatx4){0.f,0.f,0.f,0.f};
    #pragma unroll
    for (int kt = 0; kt < 8; ++kt){
      short8 b[4];
      #pragma unroll
      for (int ni = 0; ni < 4; ++ni)
        b[ni] = *(const short8*)&Bs[(wn*64 + ni*16 + l16)*264 + kt*32 + quad*8];
      #pragma unroll
      for (int mi = 0; mi < 4; ++mi)
        #pragma unroll
        for (int ni = 0; ni < 4; ++ni)
          acc[mi][ni] = __builtin_amdgcn_mfma_f32_16x16x32_bf16(Af[mi][kt], b[ni], acc[mi][ni], 0,0,0);
    }
    ushort* Tw = Tb + w*16*72;
    #pragma unroll
    for (int mi = 0; mi < 4; ++mi){
      #pragma unroll
      for (int ni = 0; ni < 4; ++ni)
        #pragma unroll
        for (int r = 0; r < 4; ++r)
          Tw[(quad*4 + r)*72 + ni*16 + l16] = f2bf(acc[mi][ni][r]);
      // wave-internal LDS round-trip (same-wave DS ops are in-order)
      #pragma unroll
      for (int i = 0; i < 2; ++i){
        int rr = i*8 + (lane >> 3);
        int cc = lane & 7;
        int grow = bm*128 + wm*64 + mi*16 + rr;
        *(uint4*)(xp + (size_t)grow*768 + bn*128 + wn*64 + cc*8) = *(const uint4*)&Tw[rr*72 + cc*8];
      }
    }
  }
}

// Persistent 16-step scan, weights fully register-resident.
// grid 256 x 512 thr (8 waves, 2/SIMD, 256-VGPR budget). Block owns 16 rows.
// Wave owns 96 cols: Wf[6][8] = 192 VGPRs preloaded once -> zero weight traffic
// in the loop. xp double-buffered in LDS via global_load_lds. 2 barriers/step.
// dyn LDS = 8448(hA) + 49408(Ep) + 49152(xs dbuf) = 107008 B -> 1 block/CU.
__global__ __launch_bounds__(512,2) void k_scan(
    const ushort* __restrict__ Whp, const ushort* __restrict__ xp,
    const float* __restrict__ bx, const float* __restrict__ bh,
    const float* __restrict__ h_in, const ushort* __restrict__ hbf_in,
    float* __restrict__ h_out, ushort* __restrict__ hbf_out, int first)
{
  extern __shared__ __align__(16) char smem[];
  ushort* hA = (ushort*)smem;                   // [16][264]
  float*  Ep = (float*)(smem + 8448);           // [16][772]
  ushort* xs = (ushort*)(smem + 57856);         // [2][16][768]

  const int tid = threadIdx.x;
  const int lane = tid & 63, w = tid >> 6;      // 8 waves; wave cols w*96..+96
  const int quad = lane >> 4, l16 = lane & 15;
  const int n0 = blockIdx.x*16;
  const int u = tid & 255, rq = tid >> 8;       // gate: 8 rows per thread

  // preload Wh fragments: 6 col-tiles x 8 kt (192 VGPRs, persistent)
  short8 Wf[6][8];
  #pragma unroll
  for (int ni = 0; ni < 6; ++ni)
    #pragma unroll
    for (int kt = 0; kt < 8; ++kt)
      Wf[ni][kt] = *(const short8*)(Whp + ((size_t)(w*96 + ni*16 + l16))*H_ + kt*32 + quad*8);

  float hreg[8];
  if (first){
    #pragma unroll
    for (int r = 0; r < 8; ++r) hreg[r] = 0.f;
    for (int i = tid; i < 16*264; i += 512) hA[i] = 0;
  } else {
    #pragma unroll
    for (int r = 0; r < 8; ++r){
      int row = rq*8 + r;
      hreg[r] = h_in[(size_t)(n0+row)*H_ + u];
      hA[row*264 + u] = hbf_in[(size_t)(n0+row)*H_ + u];
    }
  }
  const float b0 = bx[u] + bh[u];
  const float b1 = bx[256+u] + bh[256+u];
  const float b2x = bx[512+u], b2h = bh[512+u];

  // pre-stage xs[0] (24576 B = 24 wave-chunks of 1024 B; 3 per wave)
  {
    const ushort* src = xp + (size_t)n0*768;
    #pragma unroll
    for (int t = 0; t < 3; ++t){
      int off = (w*3 + t)*512;   // ushorts
      gl_lds16(src + off + lane*8, xs + off);
    }
  }
  __syncthreads();   // hA init + xs[0] visible

  for (int l = 0; l < 16; ++l){
    // prefetch next step's xp slice into the other buffer
    if (l < 15){
      const ushort* src = xp + (size_t)(l+1)*N_*768 + (size_t)n0*768;
      ushort* dst = xs + ((l+1)&1)*12288;
      #pragma unroll
      for (int t = 0; t < 3; ++t){
        int off = (w*3 + t)*512;
        gl_lds16(src + off + lane*8, dst + off);
      }
    }
    // MFMA phase: h @ Wh^T for this wave's 96 cols
    floatx4 acc[6];
    #pragma unroll
    for (int i = 0; i < 6; ++i) acc[i] = (floatx4){0.f,0.f,0.f,0.f};
    #pragma unroll
    for (int kt = 0; kt < 8; ++kt){
      short8 a = *(const short8*)&hA[l16*264 + kt*32 + quad*8];
      #pragma unroll
      for (int ni = 0; ni < 6; ++ni)
        acc[ni] = __builtin_amdgcn_mfma_f32_16x16x32_bf16(a, Wf[ni][kt], acc[ni], 0,0,0);
    }
    // Ep write (prev gate's Ep reads finished before end-of-prev-step barrier)
    #pragma unroll
    for (int ni = 0; ni < 6; ++ni)
      #pragma unroll
      for (int r = 0; r < 4; ++r)
        Ep[(quad*4 + r)*772 + w*96 + ni*16 + l16] = acc[ni][r];
    __syncthreads();   // Ep visible; xs prefetch drained (vmcnt at barrier)
    // gate
    const ushort* xc = xs + (l&1)*12288;
    #pragma unroll
    for (int r = 0; r < 8; ++r){
      int row = rq*8 + r;
      float hr = Ep[row*772 +       u];
      float hz = Ep[row*772 + 256 + u];
      float hn = Ep[row*772 + 512 + u];
      float xr = bf2f(xc[row*768 +       u]);
      float xz = bf2f(xc[row*768 + 256 + u]);
      float xn = bf2f(xc[row*768 + 512 + u]);
      float rg = 1.f/(1.f + __expf(-(xr + hr + b0)));
      float zg = 1.f/(1.f + __expf(-(xz + hz + b1)));
      float na = xn + b2x + rg*(hn + b2h);
      float ng = 1.f - 2.f/(1.f + __expf(2.f*na));
      hreg[r] = ng*(1.f - zg) + hreg[r]*zg;
      hA[row*264 + u] = f2bf(hreg[r]);
    }
    __syncthreads();   // hA + xs-buffer reuse safe for next step
  }
  #pragma unroll
  for (int r = 0; r < 8; ++r){
    int row = rq*8 + r;
    h_out[(size_t)(n0+row)*H_ + u] = hreg[r];
    hbf_out[(size_t)(n0+row)*H_ + u] = f2bf(hreg[r]);
  }
}

// c = prelu(prelu(h,a1) @ lin_W + lin_b, a2) -> out[..., 256:512]
__global__ __launch_bounds__(256) void k_final(
    const float* __restrict__ h, const float* __restrict__ a1p,
    const float* __restrict__ lin_W, const float* __restrict__ lin_b,
    const float* __restrict__ a2p, float* __restrict__ out){
  const int nbase = blockIdx.x*16, tid = threadIdx.x;
  __shared__ float hp[16][H_];
  const float a1 = a1p[0], a2 = a2p[0];
  for (int i = tid; i < 16*H_; i += 256)
    hp[i>>8][i&255] = prelu_f(h[(size_t)(nbase + (i>>8))*H_ + (i&255)], a1);
  __syncthreads();
  float acc[16];
  const float b = lin_b[tid];
  #pragma unroll
  for (int r = 0; r < 16; ++r) acc[r] = b;
  for (int j = 0; j < H_; ++j){
    float w = lin_W[(size_t)j*H_ + tid];
    #pragma unroll
    for (int r = 0; r < 16; ++r) acc[r] += hp[r][j]*w;
  }
  for (int r = 0; r < 16; ++r)
    out[(size_t)(nbase+r)*512 + 256 + tid] = prelu_f(acc[r], a2);
}

extern "C" void kernel_launch(void* const* d_in, const int* in_sizes, int n_in,
                              void* d_out, int out_size, void* d_ws, size_t ws_size,
                              hipStream_t stream) {
  (void)in_sizes; (void)n_in; (void)out_size; (void)ws_size;
  const float* obs      = (const float*)d_in[0];
  const float* comm     = (const float*)d_in[1];
  const float* obs_emb  = (const float*)d_in[2];
  const float* obs_a_emb= (const float*)d_in[3];
  const float* obs_W    = (const float*)d_in[4];
  const float* obs_b    = (const float*)d_in[5];
  const float* obs_a    = (const float*)d_in[6];
  const float* comm_emb = (const float*)d_in[7];
  const float* comm_a   = (const float*)d_in[8];
  const float* cw1      = (const float*)d_in[9];
  const float* cb1      = (const float*)d_in[10];
  const float* cw3      = (const float*)d_in[11];
  const float* cb3      = (const float*)d_in[12];
  const float* cw5      = (const float*)d_in[13];
  const float* cb5      = (const float*)d_in[14];
  const float* cw7      = (const float*)d_in[15];
  const float* cb7      = (const float*)d_in[16];
  const float* bn_g     = (const float*)d_in[17];
  const float* bn_b     = (const float*)d_in[18];
  const float* cnn_a    = (const float*)d_in[19];
  const float* Wx       = (const float*)d_in[20];
  const float* bx       = (const float*)d_in[21];
  const float* Wh       = (const float*)d_in[22];
  const float* bh       = (const float*)d_in[23];
  const float* lin_a1   = (const float*)d_in[24];
  const float* lin_W    = (const float*)d_in[25];
  const float* lin_b    = (const float*)d_in[26];
  const float* lin_a2   = (const float*)d_in[27];
  float* out = (float*)d_out;

  char* ws = (char*)d_ws;
  float*  contrib = (float*)(ws + 0);            // 4,194,304
  float*  P       = (float*)(ws + 4194304);      // 131,072
  int*    idx     = (int*)  (ws + 4325376);      // 524,288
  int*    tok     = (int*)  (ws + 4849664);      // 524,288
  float*  stats   = (float*)(ws + 5373952);      // 2,048
  float*  ss      = (float*)(ws + 5376000);      // 2,048
  ushort* WxT3    = (ushort*)(ws + 5378048);     // 393,216
  ushort* WhT3p   = (ushort*)(ws + 5771264);     // 393,216
  float*  h_a     = (float*)(ws + 6164480);      // 4,194,304
  float*  h_b     = (float*)(ws + 10358784);     // 4,194,304
  ushort* hbf_a   = (ushort*)(ws + 14553088);    // 2,097,152
  ushort* hbf_b   = (ushort*)(ws + 16650240);    // 2,097,152
  ushort* ynorm   = (ushort*)(ws + 18747392);    // 67,108,864
  ushort* xp      = (ushort*)(ws + 85856256);    // 100,663,296

  hipMemsetAsync(stats, 0, 512*sizeof(float), stream);

  k_idx<<<1024, 256, 0, stream>>>(obs, idx);
  k_tok<<<512, 256, 0, stream>>>(comm, tok);
  k_WT3<<<768, 256, 0, stream>>>(Wx, Wh, WxT3, WhT3p);
  k_P<<<dim3(16,32), 64, 0, stream>>>(comm_emb, comm_a, cw1, cw3, cw5, cw7, P);
  k_contrib<<<dim3(32,8), 256, 0, stream>>>(obs_emb, obs_a_emb, obs_W, contrib);
  k_obs_o<<<4096, 256, 0, stream>>>(idx, contrib, obs_b, obs_a, out);
  k_conv_stats<<<dim3(256,4), 256, 0, stream>>>(tok, P, cb1, cb3, cb5, cb7, stats);
  k_bn_fin<<<1, 256, 0, stream>>>(stats, bn_g, bn_b, ss);
  k_conv_apply<<<dim3(256,4), 256, 0, stream>>>(tok, P, cb1, cb3, cb5, cb7, ss, cnn_a, ynorm);

  // half 0: l = 0..15
  k_xproj<<<512, 256, 76800, stream>>>(ynorm, WxT3, xp);
  k_scan<<<256, 512, 107008, stream>>>(WhT3p, xp, bx, bh, h_a, hbf_a, h_a, hbf_a, 1);
  // half 1: l = 16..31
  k_xproj<<<512, 256, 76800, stream>>>(ynorm + (size_t)16*N_*H_, WxT3, xp);
  k_scan<<<256, 512, 107008, stream>>>(WhT3p, xp, bx, bh, h_a, hbf_a, h_b, hbf_b, 0);

  k_final<<<256, 256, 0, stream>>>(h_b, lin_a1, lin_W, lin_b, lin_a2, out);
}